// Round 8
// baseline (349.244 us; speedup 1.0000x reference)
//
#include <hip/hip_runtime.h>
#include <math.h>

#define TOPK 100
#define HW 65536                   // 256*256
#define SLICE_STRIDE (7*HW)        // 458752
#define NBATCH 32
#define NBOX 200
#define HM (3*HW)                  // 196608 heatmap elems per slice
#define CAP 4096                   // candidate cap (no-ws fallback path)
#define NPART 8                    // collect parts per slice
#define PPART 64                   // key slots per part
#define KEYS_BASE 256              // u64 index where keys start (2048B cnt region)
#define WS_NEED ((size_t)(2048 + 64 * NPART * PPART * 8))
#define TKEYS 0xC0400000u          // fkey(3.0f). N(0,1): per-part (24576 elems)
                                   // mean 33.2 sigma 5.75 -> P(>64) ~ 5.5sigma;
                                   // per-slice 265+-16 -> P(<100) ~ 10sigma.
                                   // Exact in-kernel fallback guards regardless.

// Order-preserving float->uint key: f1 > f2  <=>  key(f1) > key(f2)
__device__ __forceinline__ unsigned fkey(float f) {
    unsigned u = __float_as_uint(f);
    return (u & 0x80000000u) ? ~u : (u | 0x80000000u);
}

// Runtime-slot selects over 4-entry register arrays (constant indices only)
__device__ __forceinline__ float sel4(const float a[4], int s) {
    float r = a[0];
    r = (s == 1) ? a[1] : r;
    r = (s == 2) ? a[2] : r;
    r = (s == 3) ? a[3] : r;
    return r;
}
__device__ __forceinline__ int sel4i(const int a[4], int s) {
    int r = a[0];
    r = (s == 1) ? a[1] : r;
    r = (s == 2) ? a[2] : r;
    r = (s == 3) ? a[3] : r;
    return r;
}

#if defined(__has_builtin) && __has_builtin(__builtin_amdgcn_update_dpp)
// ---- 32-bit wave max (round-4 verified DPP network) ----
#define DPP32_STEP(ctrl)                                                        \
    {                                                                           \
        unsigned tmp_ = (unsigned)__builtin_amdgcn_update_dpp(                  \
            (int)x, (int)x, (ctrl), 0xF, 0xF, false);                           \
        x = x > tmp_ ? x : tmp_;                                                \
    }
__device__ __forceinline__ unsigned wave_umax32(unsigned x) {
    DPP32_STEP(0x111) DPP32_STEP(0x112) DPP32_STEP(0x114)
    DPP32_STEP(0x118) DPP32_STEP(0x142) DPP32_STEP(0x143)
    return (unsigned)__builtin_amdgcn_readlane((int)x, 63);
}
// ---- 64-bit wave max (round-5..7 verified) — used by exact fallback ----
#define DPP64_STEP(ctrl)                                                        \
    {                                                                           \
        unsigned lo = (unsigned)x, hi = (unsigned)(x >> 32);                    \
        unsigned olo = (unsigned)__builtin_amdgcn_update_dpp((int)lo, (int)lo,  \
                                                             (ctrl), 0xF, 0xF, false); \
        unsigned ohi = (unsigned)__builtin_amdgcn_update_dpp((int)hi, (int)hi,  \
                                                             (ctrl), 0xF, 0xF, false); \
        unsigned long long o = ((unsigned long long)ohi << 32) | olo;           \
        x = (o > x) ? o : x;                                                    \
    }
__device__ __forceinline__ unsigned long long wave_umax64(unsigned long long x) {
    DPP64_STEP(0x111) DPP64_STEP(0x112) DPP64_STEP(0x114)
    DPP64_STEP(0x118) DPP64_STEP(0x142) DPP64_STEP(0x143)
    unsigned rlo = (unsigned)__builtin_amdgcn_readlane((int)(unsigned)x, 63);
    unsigned rhi = (unsigned)__builtin_amdgcn_readlane((int)(unsigned)(x >> 32), 63);
    return ((unsigned long long)rhi << 32) | rlo;
}
__device__ __forceinline__ int lane_geti(int v, int lane) {
    return __builtin_amdgcn_readlane(v, lane);
}
__device__ __forceinline__ float lane_getf(const float a[4], int slot, int lane) {
    return __uint_as_float((unsigned)__builtin_amdgcn_readlane(
        (int)__float_as_uint(sel4(a, slot)), lane));
}
#else
__device__ __forceinline__ unsigned wave_umax32(unsigned x) {
    #pragma unroll
    for (int off = 32; off > 0; off >>= 1) {
        unsigned o = (unsigned)__shfl_xor((int)x, off);
        x = x > o ? x : o;
    }
    return x;
}
__device__ __forceinline__ unsigned long long wave_umax64(unsigned long long x) {
    #pragma unroll
    for (int off = 32; off > 0; off >>= 1) {
        unsigned long long o = __shfl_xor(x, off);
        if (o > x) x = o;
    }
    return x;
}
__device__ __forceinline__ int lane_geti(int v, int lane) { return __shfl(v, lane); }
__device__ __forceinline__ float lane_getf(const float a[4], int slot, int lane) {
    return __shfl(sel4(a, slot), lane);
}
#endif

// ===========================================================================
// Kernel 1: threshold collect. 512 blocks x 1024 threads; block (slice,part)
// exclusively owns cnt[slice*8+part] and keys[slice*512 + part*64 + ...] —
// no cross-block atomics, no pre-zeroing (reads guarded by counts).
// ===========================================================================
__global__ __launch_bounds__(1024) void kcollect(const float* __restrict__ x,
                                                 unsigned long long* __restrict__ ws) {
    __shared__ unsigned shCnt;
    const int bid = blockIdx.x;
    const int slice = bid >> 3, part = bid & 7;
    const int t = threadIdx.x;
    const float* xb = x + (size_t)slice * SLICE_STRIDE;
    const float4* xb4 = (const float4*)xb;
    unsigned* cnt = (unsigned*)ws;                          // u32[64*8]
    unsigned long long* keys = ws + KEYS_BASE;

    if (t == 0) shCnt = 0u;
    __syncthreads();

    const int i0 = part * (HM / 4 / NPART);                 // 6144 float4/part
    const int i1 = i0 + (HM / 4 / NPART);
    for (int i = i0 + t; i < i1; i += 1024) {
        float4 v = xb4[i];
        float a[4] = {v.x, v.y, v.z, v.w};
        #pragma unroll
        for (int q = 0; q < 4; ++q) {
            unsigned vk = fkey(a[q]);
            if (vk >= TKEYS) {
                unsigned pos = atomicAdd(&shCnt, 1u);
                if (pos < PPART)
                    keys[(size_t)slice * (NPART * PPART) + part * PPART + pos] =
                        ((unsigned long long)vk << 32) |
                        (unsigned)~(unsigned)(i * 4 + q);
            }
        }
    }
    __syncthreads();
    if (t == 0) cnt[slice * NPART + part] = shCnt;          // raw (may > PPART)
}

// ---------------------------------------------------------------------------
// Exact selection fallback (round-0 verified argmax loop; 512-thread form).
// ---------------------------------------------------------------------------
__device__ void fb_select(const float* xb, unsigned long long* fkrow,
                          unsigned* selmask, float* rv, int* ri, int t) {
    for (int i = t; i < HM / 32; i += 512) selmask[i] = 0u;
    __syncthreads();
    for (int r = 0; r < TOPK; ++r) {
        float bv = -INFINITY; int bi = 0x7FFFFFFF;
        for (int i = t; i < HM; i += 512) {
            if (!((selmask[i >> 5] >> (i & 31)) & 1u)) {
                float v = xb[i];
                if (v > bv || (v == bv && i < bi)) { bv = v; bi = i; }
            }
        }
        rv[t] = bv; ri[t] = bi;
        __syncthreads();
        for (int off = 256; off > 0; off >>= 1) {
            if (t < off) {
                float ov = rv[t + off]; int oi = ri[t + off];
                if (ov > rv[t] || (ov == rv[t] && oi < ri[t])) { rv[t] = ov; ri[t] = oi; }
            }
            __syncthreads();
        }
        if (t == 0) {
            int w = ri[0];
            selmask[w >> 5] |= (1u << (w & 31));
            fkrow[r] = ((unsigned long long)fkey(rv[0]) << 32) |
                       (unsigned)~(unsigned)w;
        }
        __syncthreads();
    }
}

// ===========================================================================
// Kernel 2: 32 blocks x 512 threads.
// Phase A: gather <=512 keys per slice (halves in parallel), bitonic sort,
//          decode top-100 per slice -> LDS (slots 0..199 = ranks).
// OV:      per-box "has any overlapping partner" flags (boxes immutable).
// Phase B: wave-0 ORDER-FREE selection loop: 32-bit DPP argmax on score
//          bits; winner writes its own registers to output row i; decay only
//          when the winner's OV flag is set (skip is bit-exact: all inter==0
//          => w=expf(-0.0f)=1.0f => scores unchanged). ANY tie at the top or
//          an all-zero max => exact fallback: rerun the round-7-VERIFIED
//          virtual-position loop from the pristine LDS state.
// ===========================================================================
__global__ __launch_bounds__(512) void knms7(const float* __restrict__ x,
                                             const unsigned long long* __restrict__ ws,
                                             float* __restrict__ out) {
    __shared__ unsigned long long shpool64[3584];   // 28 KB union
    __shared__ unsigned long long fk[2][TOPK];
    __shared__ float4 bxs4[NBOX];
    __shared__ float scs[NBOX];
    __shared__ float cl[NBOX];
    __shared__ int ovf[NBOX];
    __shared__ int badf[2];

    unsigned long long* skey = shpool64;            // [2][512] u64 = 8 KB
    unsigned* selmask = (unsigned*)shpool64;        // fb: [6144] u32 = 24 KB
    float* rv = (float*)(selmask + 6144);           // fb: [512]
    int* ri = (int*)(selmask + 6656);               // fb: [512]

    const int b = blockIdx.x, t = threadIdx.x;
    const unsigned* cnt = (const unsigned*)ws;
    const unsigned long long* keys = ws + KEYS_BASE;

    if (t < 2) {
        unsigned tot = 0; int bad = 0;
        for (int p8 = 0; p8 < NPART; ++p8) {
            unsigned c = cnt[(2 * b + t) * NPART + p8];
            tot += c;
            if (c > PPART) bad = 1;
        }
        if (tot < TOPK) bad = 1;
        badf[t] = bad;
    }
    __syncthreads();

    if (badf[0]) fb_select(x + (size_t)(2 * b + 0) * SLICE_STRIDE, fk[0],
                           selmask, rv, ri, t);
    if (badf[1]) fb_select(x + (size_t)(2 * b + 1) * SLICE_STRIDE, fk[1],
                           selmask, rv, ri, t);

    // ---- phase A: gather + bitonic sort (256 threads per half) ----
    const int half = t >> 8, tt = t & 255;
    const int slice = 2 * b + half;
    for (int e = tt; e < 512; e += 256) {
        int part = e >> 6, off = e & 63;
        unsigned c = cnt[slice * NPART + part];
        bool valid = (!badf[half]) && ((unsigned)off < c);
        skey[half * 512 + e] = valid
            ? keys[(size_t)slice * (NPART * PPART) + part * PPART + off] : 0ull;
    }
    __syncthreads();
    for (int k = 2; k <= 512; k <<= 1) {
        for (int j = k >> 1; j > 0; j >>= 1) {
            for (int e = tt; e < 512; e += 256) {
                int i = e, ixj = i ^ j;
                if (ixj > i) {
                    unsigned long long a = skey[half * 512 + i];
                    unsigned long long c2 = skey[half * 512 + ixj];
                    bool sw = ((i & k) == 0) ? (a < c2) : (a > c2);
                    if (sw) { skey[half * 512 + i] = c2; skey[half * 512 + ixj] = a; }
                }
            }
            __syncthreads();
        }
    }

    // ---- decode top-100 per slice (formulas verbatim, verified r2-r7) ----
    if (t < NBOX) {
        const int sB = t / TOPK, rank = t - sB * TOPK;
        const int sl2 = 2 * b + sB;
        unsigned long long K = badf[sB] ? fk[sB][rank] : skey[sB * 512 + rank];
        unsigned vk = (unsigned)(K >> 32);
        unsigned idx = ~((unsigned)K);
        unsigned u = (vk & 0x80000000u) ? (vk & 0x7FFFFFFFu) : ~vk;
        float z = __uint_as_float(u);               // exact original logit
        int c = (int)(idx >> 16);                   // HW == 2^16
        int rem = (int)(idx & 0xFFFFu);
        const float* xb = x + (size_t)sl2 * SLICE_STRIDE;
        float ysf = (float)(rem >> 8);
        float xsf = (float)(rem & 255);
        float offx = xb[3 * HW + rem];
        float offy = xb[4 * HW + rem];
        float bw = xb[5 * HW + rem] * 4.0f;
        float bh = xb[6 * HW + rem] * 4.0f;
        float cx = (xsf + offx) * 4.0f;
        float cy = (ysf + offy) * 4.0f;
        bxs4[t] = make_float4(cx - bw * 0.5f, cy - bh * 0.5f,
                              cx + bw * 0.5f, cy + bh * 0.5f);
        float sg = 1.0f / (1.0f + expf(-z));
        scs[t] = (sg > 0.1f) ? sg : 0.0f;
        cl[t] = (float)c;
    }
    __syncthreads();

    // ---- OV flags: box t overlaps (inter>0) any other box? ----
    if (t < NBOX) {
        float4 me = bxs4[t];
        int ov = 0;
        for (int q = 0; q < NBOX; ++q) {
            if (q == t) continue;
            float4 o = bxs4[q];
            float gx = fminf(me.z, o.z) - fmaxf(me.x, o.x) + 1.0f;
            float gy = fminf(me.w, o.w) - fmaxf(me.y, o.y) + 1.0f;
            if (gx > 0.0f && gy > 0.0f) { ov = 1; break; }
        }
        ovf[t] = ov;
    }
    __syncthreads();

    // ---- phase B: wave 0 only ----
    if (t < 64) {
        float X1[4], Y1[4], X2[4], Y2[4], SC[4], CL4[4], AR[4];
        unsigned KB[4]; int OV4[4];
        unsigned selb = 0u;
        #pragma unroll
        for (int sl = 0; sl < 4; ++sl) {
            int p = sl * 64 + t;
            int q = (p < NBOX) ? p : 0;
            float4 bb = bxs4[q];
            X1[sl] = bb.x; Y1[sl] = bb.y; X2[sl] = bb.z; Y2[sl] = bb.w;
            SC[sl] = (p < NBOX) ? scs[q] : 0.0f;
            CL4[sl] = cl[q];
            AR[sl] = (X2[sl] - X1[sl] + 1.0f) * (Y2[sl] - Y1[sl] + 1.0f);
            KB[sl] = (p < NBOX) ? __float_as_uint(SC[sl]) : 0u;
            OV4[sl] = (p < NBOX) ? ovf[q] : 0;
            if (p >= NBOX) selb |= (1u << sl);      // phantoms pre-"selected"
        }

        float* ob  = out + (size_t)b * NBOX * 4;
        float* oc  = out + (size_t)NBATCH * NBOX * 4 + b * NBOX;
        float* os  = out + (size_t)NBATCH * NBOX * 5 + b * NBOX;
        float* okp = out + (size_t)NBATCH * NBOX * 6 + b * NBOX;

        bool fb = false;
        for (int i = 0; i < NBOX; ++i) {
            unsigned lb = KB[0] > KB[1] ? KB[0] : KB[1];
            unsigned lb2 = KB[2] > KB[3] ? KB[2] : KB[3];
            lb = lb > lb2 ? lb : lb2;
            unsigned smax = wave_umax32(lb);
            if (smax == 0u) { fb = true; break; }   // mass zero-tie -> exact path

            unsigned long long mk = __ballot(lb == smax);
            if (__popcll(mk) > 1ull) { fb = true; break; }  // cross-lane tie
            int wl = (int)__builtin_ctzll(mk);
            int nm = (KB[0] == smax) + (KB[1] == smax) +
                     (KB[2] == smax) + (KB[3] == smax);
            int fs = 3;
            fs = (KB[2] == smax) ? 2 : fs;
            fs = (KB[1] == smax) ? 1 : fs;
            fs = (KB[0] == smax) ? 0 : fs;
            if (lane_geti(nm, wl) > 1) { fb = true; break; } // intra-lane tie
            int ws_ = lane_geti(fs, wl);
            int wov = lane_geti(sel4i(OV4, ws_), wl);

            // mark winner selected (before decay; reference decays pos>i only)
            if (t == wl) {
                selb |= (1u << ws_);
                #pragma unroll
                for (int sl = 0; sl < 4; ++sl) if (sl == ws_) KB[sl] = 0u;
                // output row i straight from winner-lane registers
                float4 bb = make_float4(sel4(X1, ws_), sel4(Y1, ws_),
                                        sel4(X2, ws_), sel4(Y2, ws_));
                *(float4*)(ob + (size_t)i * 4) = bb;
                float bsc = sel4(SC, ws_);
                oc[i]  = sel4(CL4, ws_);
                os[i]  = bsc;
                okp[i] = (bsc > 0.1f) ? 1.0f : 0.0f;
            }

            if (wov) {
                // winner overlaps someone: full decay pass (formulas verbatim)
                float pvx1 = lane_getf(X1, ws_, wl);
                float pvy1 = lane_getf(Y1, ws_, wl);
                float pvx2 = lane_getf(X2, ws_, wl);
                float pvy2 = lane_getf(Y2, ws_, wl);
                float area_i = lane_getf(AR, ws_, wl);
                #pragma unroll
                for (int sl = 0; sl < 4; ++sl) {
                    if (!((selb >> sl) & 1u)) {
                        float xx1 = fmaxf(pvx1, X1[sl]);
                        float yy1 = fmaxf(pvy1, Y1[sl]);
                        float xx2 = fminf(pvx2, X2[sl]);
                        float yy2 = fminf(pvy2, Y2[sl]);
                        float inter = fmaxf(0.0f, xx2 - xx1 + 1.0f) *
                                      fmaxf(0.0f, yy2 - yy1 + 1.0f);
                        float iou = inter / (area_i + AR[sl] - inter);
                        float w = expf(-(iou * iou) / 0.5f);
                        SC[sl] = w * SC[sl];
                        KB[sl] = __float_as_uint(SC[sl]);
                    }
                }
            }
            // wov==0: every inter==0 -> w=expf(-0.0f)=1.0f -> SC bit-unchanged
        }

        if (fb) {
            // ======= EXACT FALLBACK: round-7-verified virtual-position loop
            // ======= rerun from the PRISTINE LDS decode (never modified).
            float aX1[4], aY1[4], aX2[4], aY2[4], aSC[4], aCL[4], aAR[4];
            unsigned CP[4];
            #pragma unroll
            for (int sl = 0; sl < 4; ++sl) {
                int p = sl * 64 + t;
                int q = (p < NBOX) ? p : 0;
                float4 bb = bxs4[q];
                aX1[sl] = bb.x; aY1[sl] = bb.y; aX2[sl] = bb.z; aY2[sl] = bb.w;
                aSC[sl] = (p < NBOX) ? scs[q] : 0.0f;
                aCL[sl] = cl[q];
                CP[sl] = (unsigned)p;
                aAR[sl] = (aX2[sl] - aX1[sl] + 1.0f) * (aY2[sl] - aY1[sl] + 1.0f);
            }
            for (int i = 0; i < NBOX; ++i) {
                const unsigned ui = (unsigned)i;
                unsigned long long loc = 0ull;
                #pragma unroll
                for (int sl = 0; sl < 4; ++sl) {
                    unsigned cd = ~((CP[sl] << 8) | (unsigned)(sl * 64 + t));
                    unsigned long long k =
                        ((unsigned long long)__float_as_uint(aSC[sl]) << 32) | cd;
                    if (CP[sl] >= ui && k > loc) loc = k;
                }
                unsigned long long kmax = wave_umax64(loc);
                if ((unsigned)(kmax >> 32) == 0u) break;
                unsigned w32 = ~((unsigned)kmax);
                unsigned m = w32 >> 8;
                int worig = (int)(w32 & 0xFFu);
                int lane_m = worig & 63, slot_m = worig >> 6;
                float pvx1 = lane_getf(aX1, slot_m, lane_m);
                float pvy1 = lane_getf(aY1, slot_m, lane_m);
                float pvx2 = lane_getf(aX2, slot_m, lane_m);
                float pvy2 = lane_getf(aY2, slot_m, lane_m);
                float area_i = lane_getf(aAR, slot_m, lane_m);
                #pragma unroll
                for (int sl = 0; sl < 4; ++sl) {
                    unsigned cp = CP[sl];
                    unsigned ncp = (cp == ui) ? m : cp;
                    ncp = (cp == m) ? ui : ncp;
                    CP[sl] = ncp;
                }
                float intr[4]; bool anyp = false;
                #pragma unroll
                for (int sl = 0; sl < 4; ++sl) {
                    int p = sl * 64 + t;
                    bool act = (p < NBOX) && (CP[sl] > ui);
                    float xx1 = fmaxf(pvx1, aX1[sl]);
                    float yy1 = fmaxf(pvy1, aY1[sl]);
                    float xx2 = fminf(pvx2, aX2[sl]);
                    float yy2 = fminf(pvy2, aY2[sl]);
                    float inter = fmaxf(0.0f, xx2 - xx1 + 1.0f) *
                                  fmaxf(0.0f, yy2 - yy1 + 1.0f);
                    intr[sl] = inter;
                    anyp |= (act && inter != 0.0f);
                }
                if (__ballot(anyp) != 0ull) {
                    #pragma unroll
                    for (int sl = 0; sl < 4; ++sl) {
                        int p = sl * 64 + t;
                        if ((p < NBOX) && (CP[sl] > ui)) {
                            float iou = intr[sl] / (area_i + aAR[sl] - intr[sl]);
                            float w = expf(-(iou * iou) / 0.5f);
                            aSC[sl] = w * aSC[sl];
                        }
                    }
                }
            }
            #pragma unroll
            for (int sl = 0; sl < 4; ++sl) {
                int p = sl * 64 + t;
                if (p < NBOX) {
                    unsigned q = CP[sl];
                    ob[q * 4 + 0] = aX1[sl];
                    ob[q * 4 + 1] = aY1[sl];
                    ob[q * 4 + 2] = aX2[sl];
                    ob[q * 4 + 3] = aY2[sl];
                    oc[q]  = aCL[sl];
                    os[q]  = aSC[sl];
                    okp[q] = (aSC[sl] > 0.1f) ? 1.0f : 0.0f;
                }
            }
        }
    }
}

// ===========================================================================
// FALLBACK PATH (round-2 verified kernels, verbatim) — used if ws too small
// ===========================================================================
__global__ __launch_bounds__(1024) void ktopk(const float* __restrict__ x,
                                              float* __restrict__ out) {
    __shared__ unsigned hist[4096];
    __shared__ unsigned long long cand[CAP];
    __shared__ int shB, shB2;
    __shared__ unsigned shAbove, shNcand, shNc;

    const int slice = blockIdx.x;
    const int b = slice >> 1, s = slice & 1;
    const int t = threadIdx.x;
    const float* xb = x + (size_t)slice * SLICE_STRIDE;
    const float4* xb4 = (const float4*)xb;
    const int N4 = HM / 4;

    if (t == 0) { shB = 0; shB2 = 0; shAbove = 0u; shNcand = 0u; shNc = 0u; }
    for (int i = t; i < 4096; i += 1024) hist[i] = 0u;
    __syncthreads();

    for (int i = t; i < N4; i += 1024) {
        float4 v = xb4[i];
        float a[4] = {v.x, v.y, v.z, v.w};
        #pragma unroll
        for (int c_ = 0; c_ < 4; ++c_) {
            unsigned vk = fkey(a[c_]);
            atomicAdd(&hist[vk >> 20], 1u);
        }
    }
    __syncthreads();

    {
        unsigned* tmp = (unsigned*)cand;
        unsigned* src = hist;
        unsigned* dst = tmp;
        for (int d = 1; d < 4096; d <<= 1) {
            for (int i = t; i < 4096; i += 1024) {
                unsigned v = src[i];
                if (i + d < 4096) v += src[i + d];
                dst[i] = v;
            }
            __syncthreads();
            unsigned* sw = src; src = dst; dst = sw;
        }
        for (int i = t; i < 4096; i += 1024) {
            unsigned sb = src[i];
            unsigned sn = (i < 4095) ? src[i + 1] : 0u;
            if (sb >= TOPK && sn < TOPK) { shB = i; shAbove = sn; shNcand = sb; }
        }
        __syncthreads();
    }

    const bool refine = (shNcand > CAP);
    if (refine) {
        for (int i = t; i < 4096; i += 1024) hist[i] = 0u;
        __syncthreads();
        const unsigned Bv = (unsigned)shB;
        for (int i = t; i < N4; i += 1024) {
            float4 v = xb4[i];
            float a[4] = {v.x, v.y, v.z, v.w};
            #pragma unroll
            for (int c_ = 0; c_ < 4; ++c_) {
                unsigned vk = fkey(a[c_]);
                if ((vk >> 20) == Bv) atomicAdd(&hist[(vk >> 8) & 0xFFFu], 1u);
            }
        }
        __syncthreads();
        if (t == 0) {
            unsigned need = TOPK - shAbove, cum = 0u;
            int b2 = 4095;
            for (; b2 >= 0; --b2) { cum += hist[b2]; if (cum >= need) break; }
            shB2 = (b2 < 0) ? 0 : b2;
            shNcand = shAbove + cum;
        }
        __syncthreads();
    }

    {
        const unsigned Bv = (unsigned)shB;
        const unsigned B2v = refine ? (unsigned)shB2 : 0u;
        for (int i = t; i < N4; i += 1024) {
            float4 v = xb4[i];
            float a[4] = {v.x, v.y, v.z, v.w};
            #pragma unroll
            for (int c_ = 0; c_ < 4; ++c_) {
                unsigned vk = fkey(a[c_]);
                unsigned bin = vk >> 20;
                bool q = refine ? (bin > Bv || (bin == Bv && ((vk >> 8) & 0xFFFu) >= B2v))
                                : (bin >= Bv);
                if (q) {
                    unsigned pos = atomicAdd(&shNc, 1u);
                    if (pos < CAP)
                        cand[pos] = ((unsigned long long)vk << 32) |
                                    (unsigned)~(unsigned)(i * 4 + c_);
                }
            }
        }
        __syncthreads();
    }

    unsigned nc = shNc; if (nc > CAP) nc = CAP;
    int P = 128; while (P < (int)nc) P <<= 1;
    for (int i = (int)nc + t; i < P; i += 1024) cand[i] = 0ull;
    __syncthreads();
    for (int k = 2; k <= P; k <<= 1) {
        for (int j = k >> 1; j > 0; j >>= 1) {
            for (int i = t; i < P; i += 1024) {
                int ixj = i ^ j;
                if (ixj > i) {
                    unsigned long long a = cand[i], c2 = cand[ixj];
                    bool sw = ((i & k) == 0) ? (a < c2) : (a > c2);
                    if (sw) { cand[i] = c2; cand[ixj] = a; }
                }
            }
            __syncthreads();
        }
    }

    if (t < TOPK) {
        unsigned long long K = cand[t];
        unsigned vk = (unsigned)(K >> 32);
        unsigned idx = ~((unsigned)K);
        unsigned u = (vk & 0x80000000u) ? (vk & 0x7FFFFFFFu) : ~vk;
        float z = __uint_as_float(u);
        int c = (int)(idx >> 16);
        int rem = (int)(idx & 0xFFFFu);
        float ysf = (float)(rem >> 8);
        float xsf = (float)(rem & 255);
        float offx = xb[3 * HW + rem];
        float offy = xb[4 * HW + rem];
        float bw = xb[5 * HW + rem] * 4.0f;
        float bh = xb[6 * HW + rem] * 4.0f;
        float cx = (xsf + offx) * 4.0f;
        float cy = (ysf + offy) * 4.0f;
        int slot = s * TOPK + t;
        float* ob = out + (size_t)b * NBOX * 4;
        float* oc = out + (size_t)NBATCH * NBOX * 4 + b * NBOX;
        float* os = out + (size_t)NBATCH * NBOX * 5 + b * NBOX;
        ob[slot * 4 + 0] = cx - bw * 0.5f;
        ob[slot * 4 + 1] = cy - bh * 0.5f;
        ob[slot * 4 + 2] = cx + bw * 0.5f;
        ob[slot * 4 + 3] = cy + bh * 0.5f;
        float sg = 1.0f / (1.0f + expf(-z));
        os[slot] = (sg > 0.1f) ? sg : 0.0f;
        oc[slot] = (float)c;
    }
}

__global__ __launch_bounds__(64) void knms(float* __restrict__ out) {
    __shared__ float bxs[NBOX][4];
    __shared__ float scs[NBOX];
    __shared__ float cl[NBOX];

    const int b = blockIdx.x, t = threadIdx.x;
    float* ob  = out + (size_t)b * NBOX * 4;
    float* oc  = out + (size_t)NBATCH * NBOX * 4 + b * NBOX;
    float* os  = out + (size_t)NBATCH * NBOX * 5 + b * NBOX;
    float* okp = out + (size_t)NBATCH * NBOX * 6 + b * NBOX;

    for (int p = t; p < NBOX; p += 64) {
        bxs[p][0] = ob[p * 4 + 0];
        bxs[p][1] = ob[p * 4 + 1];
        bxs[p][2] = ob[p * 4 + 2];
        bxs[p][3] = ob[p * 4 + 3];
        scs[p] = os[p];
        cl[p]  = oc[p];
    }
    __syncthreads();

    unsigned long long local = 0ull;
    for (int p = t; p < NBOX; p += 64) {
        unsigned long long k =
            ((unsigned long long)__float_as_uint(scs[p]) << 32) | (unsigned)~(unsigned)p;
        if (k > local) local = k;
    }
    #pragma unroll
    for (int off = 32; off > 0; off >>= 1) {
        unsigned long long o = __shfl_xor(local, off);
        if (o > local) local = o;
    }
    unsigned long long kmax = local;

    for (int i = 0; i < NBOX; ++i) {
        int m = (int)(~((unsigned)kmax));
        if (t == 0 && m != i) {
            #pragma unroll
            for (int k = 0; k < 4; ++k) {
                float tmp = bxs[i][k]; bxs[i][k] = bxs[m][k]; bxs[m][k] = tmp;
            }
            float ts = scs[i]; scs[i] = scs[m]; scs[m] = ts;
            float tc = cl[i];  cl[i]  = cl[m];  cl[m]  = tc;
        }
        __syncthreads();

        float b0 = bxs[i][0], b1 = bxs[i][1], b2 = bxs[i][2], b3 = bxs[i][3];
        float area_i = (b2 - b0 + 1.0f) * (b3 - b1 + 1.0f);

        local = 0ull;
        for (int p = i + 1 + t; p < NBOX; p += 64) {
            float x1 = bxs[p][0], y1 = bxs[p][1], x2 = bxs[p][2], y2 = bxs[p][3];
            float areas = (x2 - x1 + 1.0f) * (y2 - y1 + 1.0f);
            float xx1 = fmaxf(b0, x1);
            float yy1 = fmaxf(b1, y1);
            float xx2 = fminf(b2, x2);
            float yy2 = fminf(b3, y2);
            float inter = fmaxf(0.0f, xx2 - xx1 + 1.0f) * fmaxf(0.0f, yy2 - yy1 + 1.0f);
            float iou = inter / (area_i + areas - inter);
            float w = expf(-(iou * iou) / 0.5f);
            float ns = w * scs[p];
            scs[p] = ns;
            unsigned long long k =
                ((unsigned long long)__float_as_uint(ns) << 32) | (unsigned)~(unsigned)p;
            if (k > local) local = k;
        }
        __syncthreads();
        #pragma unroll
        for (int off = 32; off > 0; off >>= 1) {
            unsigned long long o = __shfl_xor(local, off);
            if (o > local) local = o;
        }
        kmax = local;
    }
    __syncthreads();

    for (int p = t; p < NBOX; p += 64) {
        ob[p * 4 + 0] = bxs[p][0];
        ob[p * 4 + 1] = bxs[p][1];
        ob[p * 4 + 2] = bxs[p][2];
        ob[p * 4 + 3] = bxs[p][3];
        oc[p]  = cl[p];
        os[p]  = scs[p];
        okp[p] = (scs[p] > 0.1f) ? 1.0f : 0.0f;
    }
}

extern "C" void kernel_launch(void* const* d_in, const int* in_sizes, int n_in,
                              void* d_out, int out_size, void* d_ws, size_t ws_size,
                              hipStream_t stream) {
    const float* x = (const float*)d_in[0];
    float* out = (float*)d_out;
    if (d_ws != nullptr && ws_size >= WS_NEED) {
        kcollect<<<64 * NPART, 1024, 0, stream>>>(x, (unsigned long long*)d_ws);
        knms7<<<NBATCH, 512, 0, stream>>>(x, (const unsigned long long*)d_ws, out);
    } else {
        ktopk<<<2 * NBATCH, 1024, 0, stream>>>(x, out);
        knms<<<NBATCH, 64, 0, stream>>>(out);
    }
}

// Round 9
// 264.478 us; speedup vs baseline: 1.3205x; 1.3205x over previous
//
#include <hip/hip_runtime.h>
#include <math.h>

#define TOPK 100
#define HW 65536                   // 256*256
#define SLICE_STRIDE (7*HW)        // 458752
#define NBATCH 32
#define NBOX 200
#define HM (3*HW)                  // 196608 heatmap elems per slice
#define CAP 4096                   // candidate cap (no-ws fallback path)
#define NPART 8                    // collect parts per slice
#define PPART 64                   // key slots per part
#define KEYS_BASE 256              // u64 index where keys start (2048B cnt region)
#define WS_NEED ((size_t)(2048 + 64 * NPART * PPART * 8))
#define TKEYS 0xC0400000u          // fkey(3.0f). N(0,1): per-part (24576 elems)
                                   // mean 33.2 sigma 5.75 -> P(>64) ~ 5.5sigma;
                                   // per-slice 265+-16 -> P(<100) ~ 10sigma.
                                   // Exact in-kernel fallback guards regardless.

// Order-preserving float->uint key: f1 > f2  <=>  key(f1) > key(f2)
__device__ __forceinline__ unsigned fkey(float f) {
    unsigned u = __float_as_uint(f);
    return (u & 0x80000000u) ? ~u : (u | 0x80000000u);
}

// Runtime-slot select over a 4-entry register array (constant indices only)
__device__ __forceinline__ float sel4(const float a[4], int s) {
    float r = a[0];
    r = (s == 1) ? a[1] : r;
    r = (s == 2) ? a[2] : r;
    r = (s == 3) ? a[3] : r;
    return r;
}

// ---------------------------------------------------------------------------
// Wave64 u64 max-reduce via DPP (verbatim from rounds 5-7 verified kernels).
// ---------------------------------------------------------------------------
#if defined(__has_builtin) && __has_builtin(__builtin_amdgcn_update_dpp)
#define DPP64_STEP(ctrl)                                                        \
    {                                                                           \
        unsigned lo = (unsigned)x, hi = (unsigned)(x >> 32);                    \
        unsigned olo = (unsigned)__builtin_amdgcn_update_dpp((int)lo, (int)lo,  \
                                                             (ctrl), 0xF, 0xF, false); \
        unsigned ohi = (unsigned)__builtin_amdgcn_update_dpp((int)hi, (int)hi,  \
                                                             (ctrl), 0xF, 0xF, false); \
        unsigned long long o = ((unsigned long long)ohi << 32) | olo;           \
        x = (o > x) ? o : x;                                                    \
    }
__device__ __forceinline__ unsigned long long wave_umax64(unsigned long long x) {
    DPP64_STEP(0x111) DPP64_STEP(0x112) DPP64_STEP(0x114)
    DPP64_STEP(0x118) DPP64_STEP(0x142) DPP64_STEP(0x143)
    unsigned rlo = (unsigned)__builtin_amdgcn_readlane((int)(unsigned)x, 63);
    unsigned rhi = (unsigned)__builtin_amdgcn_readlane((int)(unsigned)(x >> 32), 63);
    return ((unsigned long long)rhi << 32) | rlo;
}
__device__ __forceinline__ float lane_getf(const float a[4], int slot, int lane) {
    return __uint_as_float((unsigned)__builtin_amdgcn_readlane(
        (int)__float_as_uint(sel4(a, slot)), lane));
}
#else
__device__ __forceinline__ unsigned long long wave_umax64(unsigned long long x) {
    #pragma unroll
    for (int off = 32; off > 0; off >>= 1) {
        unsigned long long o = __shfl_xor(x, off);
        if (o > x) x = o;
    }
    return x;
}
__device__ __forceinline__ float lane_getf(const float a[4], int slot, int lane) {
    return __shfl(sel4(a, slot), lane);
}
#endif

// nt-load experiment (isolated vs the round-7 274us baseline): the 48MB
// heatmap stream is read-once -> bypass L2 retention with a nontemporal hint.
typedef __attribute__((ext_vector_type(4))) float f4v;
#if defined(__has_builtin) && __has_builtin(__builtin_nontemporal_load)
#define NT_LOAD(p) __builtin_nontemporal_load(p)
#else
#define NT_LOAD(p) (*(p))
#endif

// ===========================================================================
// Kernel 1: threshold collect (round-8 shape: 512 blocks x 1024 threads;
// block (slice,part) exclusively owns cnt[slice*8+part] and its key region —
// no cross-block atomics, no pre-zeroing; reads guarded by counts).
// ===========================================================================
__global__ __launch_bounds__(1024) void kcollect(const float* __restrict__ x,
                                                 unsigned long long* __restrict__ ws) {
    __shared__ unsigned shCnt;
    const int bid = blockIdx.x;
    const int slice = bid >> 3, part = bid & 7;
    const int t = threadIdx.x;
    const float* xb = x + (size_t)slice * SLICE_STRIDE;
    const f4v* xb4 = (const f4v*)xb;
    unsigned* cnt = (unsigned*)ws;                          // u32[64*8]
    unsigned long long* keys = ws + KEYS_BASE;

    if (t == 0) shCnt = 0u;
    __syncthreads();

    const int i0 = part * (HM / 4 / NPART);                 // 6144 float4/part
    const int i1 = i0 + (HM / 4 / NPART);
    for (int i = i0 + t; i < i1; i += 1024) {
        f4v v = NT_LOAD(&xb4[i]);
        float a[4] = {v.x, v.y, v.z, v.w};
        #pragma unroll
        for (int q = 0; q < 4; ++q) {
            unsigned vk = fkey(a[q]);
            if (vk >= TKEYS) {
                unsigned pos = atomicAdd(&shCnt, 1u);
                if (pos < PPART)
                    keys[(size_t)slice * (NPART * PPART) + part * PPART + pos] =
                        ((unsigned long long)vk << 32) |
                        (unsigned)~(unsigned)(i * 4 + q);
            }
        }
    }
    __syncthreads();
    if (t == 0) cnt[slice * NPART + part] = shCnt;          // raw (may > PPART)
}

// ---------------------------------------------------------------------------
// Exact selection fallback (round-0 verified argmax loop; 1024-thread form).
// ---------------------------------------------------------------------------
__device__ void fb_select(const float* xb, unsigned long long* fkrow,
                          unsigned* selmask, float* rv, int* ri, int t) {
    for (int i = t; i < HM / 32; i += 1024) selmask[i] = 0u;
    __syncthreads();
    for (int r = 0; r < TOPK; ++r) {
        float bv = -INFINITY; int bi = 0x7FFFFFFF;
        for (int i = t; i < HM; i += 1024) {
            if (!((selmask[i >> 5] >> (i & 31)) & 1u)) {
                float v = xb[i];
                if (v > bv || (v == bv && i < bi)) { bv = v; bi = i; }
            }
        }
        rv[t] = bv; ri[t] = bi;
        __syncthreads();
        for (int off = 512; off > 0; off >>= 1) {
            if (t < off) {
                float ov = rv[t + off]; int oi = ri[t + off];
                if (ov > rv[t] || (ov == rv[t] && oi < ri[t])) { rv[t] = ov; ri[t] = oi; }
            }
            __syncthreads();
        }
        if (t == 0) {
            int w = ri[0];
            selmask[w >> 5] |= (1u << (w & 31));
            fkrow[r] = ((unsigned long long)fkey(rv[0]) << 32) |
                       (unsigned)~(unsigned)w;
        }
        __syncthreads();
    }
}

// ===========================================================================
// Kernel 2 (round-7 verified knms6, verbatim; gather adapted to NPART=8).
// 32 blocks x 1024 threads. Phase A: per half-block, gather <=512 keys,
// bitonic sort, decode top-100 per slice. Phase B: wave-0 virtual-position
// soft-NMS with decay-skip ballot (all inter==0 -> w=expf(-0.0f)=1.0f ->
// skip is bit-exact) and exact zero-score early-out.
// ===========================================================================
__global__ __launch_bounds__(1024) void knms6(const float* __restrict__ x,
                                              const unsigned long long* __restrict__ ws,
                                              float* __restrict__ out) {
    __shared__ unsigned long long shpool64[4096];   // 32 KB union
    __shared__ unsigned long long fk[2][TOPK];
    __shared__ float4 bxs4[NBOX];
    __shared__ float scs[NBOX];
    __shared__ float cl[NBOX];
    __shared__ int badf[2];

    unsigned long long* skey = shpool64;            // [2][512]
    unsigned* selmask = (unsigned*)shpool64;        // fallback: [6144]
    float* rv = (float*)(selmask + 6144);           // fallback: [1024]
    int* ri = (int*)(selmask + 7168);               // fallback: [1024]

    const int b = blockIdx.x, t = threadIdx.x;
    const unsigned* cnt = (const unsigned*)ws;
    const unsigned long long* keys = ws + KEYS_BASE;

    if (t < 2) {
        unsigned tot = 0; int bad = 0;
        for (int p8 = 0; p8 < NPART; ++p8) {
            unsigned c = cnt[(2 * b + t) * NPART + p8];
            tot += c;
            if (c > PPART) bad = 1;
        }
        if (tot < TOPK) bad = 1;
        badf[t] = bad;
    }
    __syncthreads();

    if (badf[0]) fb_select(x + (size_t)(2 * b + 0) * SLICE_STRIDE, fk[0],
                           selmask, rv, ri, t);
    if (badf[1]) fb_select(x + (size_t)(2 * b + 1) * SLICE_STRIDE, fk[1],
                           selmask, rv, ri, t);

    // ---- phase A: gather + bitonic sort 512 per half (parallel halves) ----
    const int half = t >> 9, tt = t & 511;
    const int slice = 2 * b + half;
    {
        int part = tt >> 6, off = tt & 63;          // NPART=8 x PPART=64
        unsigned c = cnt[slice * NPART + part];
        bool valid = (!badf[half]) && ((unsigned)off < c);
        skey[half * 512 + tt] = valid
            ? keys[(size_t)slice * (NPART * PPART) + part * PPART + off] : 0ull;
    }
    __syncthreads();
    for (int k = 2; k <= 512; k <<= 1) {
        for (int j = k >> 1; j > 0; j >>= 1) {
            int i = tt, ixj = i ^ j;
            if (ixj > i) {
                unsigned long long a = skey[half * 512 + i];
                unsigned long long c2 = skey[half * 512 + ixj];
                bool sw = ((i & k) == 0) ? (a < c2) : (a > c2);
                if (sw) { skey[half * 512 + i] = c2; skey[half * 512 + ixj] = a; }
            }
            __syncthreads();
        }
    }

    // ---- decode top-100 per slice (formulas verbatim, verified r2-r7) ----
    if (t < NBOX) {
        const int sB = t / TOPK, rank = t - sB * TOPK;
        const int sl2 = 2 * b + sB;
        unsigned long long K = badf[sB] ? fk[sB][rank] : skey[sB * 512 + rank];
        unsigned vk = (unsigned)(K >> 32);
        unsigned idx = ~((unsigned)K);
        unsigned u = (vk & 0x80000000u) ? (vk & 0x7FFFFFFFu) : ~vk;
        float z = __uint_as_float(u);               // exact original logit
        int c = (int)(idx >> 16);                   // HW == 2^16
        int rem = (int)(idx & 0xFFFFu);
        const float* xb = x + (size_t)sl2 * SLICE_STRIDE;
        float ysf = (float)(rem >> 8);
        float xsf = (float)(rem & 255);
        float offx = xb[3 * HW + rem];
        float offy = xb[4 * HW + rem];
        float bw = xb[5 * HW + rem] * 4.0f;
        float bh = xb[6 * HW + rem] * 4.0f;
        float cx = (xsf + offx) * 4.0f;
        float cy = (ysf + offy) * 4.0f;
        bxs4[t] = make_float4(cx - bw * 0.5f, cy - bh * 0.5f,
                              cx + bw * 0.5f, cy + bh * 0.5f);
        float sg = 1.0f / (1.0f + expf(-z));
        scs[t] = (sg > 0.1f) ? sg : 0.0f;
        cl[t] = (float)c;
    }
    __syncthreads();

    // ---- phase B: wave 0, virtual-position soft-NMS with decay-skip ----
    if (t < 64) {
        float X1[4], Y1[4], X2[4], Y2[4], SC[4], CL4[4], AR[4];
        unsigned CP[4];
        #pragma unroll
        for (int sl = 0; sl < 4; ++sl) {
            int p = sl * 64 + t;
            int q = (p < NBOX) ? p : 0;
            float4 bb = bxs4[q];
            X1[sl] = bb.x; Y1[sl] = bb.y; X2[sl] = bb.z; Y2[sl] = bb.w;
            SC[sl] = (p < NBOX) ? scs[q] : 0.0f;    // phantoms: score 0
            CL4[sl] = cl[q];
            CP[sl] = (unsigned)p;                   // phantoms: cpos 200..255
            AR[sl] = (X2[sl] - X1[sl] + 1.0f) * (Y2[sl] - Y1[sl] + 1.0f);
        }

        for (int i = 0; i < NBOX; ++i) {
            const unsigned ui = (unsigned)i;
            // 64-bit key (score bits, ~((cpos<<8)|orig)); mask cpos>=i.
            // Real boxes always occupy positions 0..199 -> winner is real.
            unsigned long long loc = 0ull;
            #pragma unroll
            for (int sl = 0; sl < 4; ++sl) {
                unsigned cd = ~((CP[sl] << 8) | (unsigned)(sl * 64 + t));
                unsigned long long k =
                    ((unsigned long long)__float_as_uint(SC[sl]) << 32) | cd;
                if (CP[sl] >= ui && k > loc) loc = k;
            }
            unsigned long long kmax = wave_umax64(loc);

            // exact early-out (verified r6/r7): max remaining +0 -> frozen
            if ((unsigned)(kmax >> 32) == 0u) break;

            unsigned w32 = ~((unsigned)kmax);       // (m<<8)|worig
            unsigned m = w32 >> 8;
            int worig = (int)(w32 & 0xFFu);
            int lane_m = worig & 63, slot_m = worig >> 6;

            float pvx1 = lane_getf(X1, slot_m, lane_m);
            float pvy1 = lane_getf(Y1, slot_m, lane_m);
            float pvx2 = lane_getf(X2, slot_m, lane_m);
            float pvy2 = lane_getf(Y2, slot_m, lane_m);
            float area_i = lane_getf(AR, slot_m, lane_m);

            // virtual swap: pos i <-> pos m
            #pragma unroll
            for (int sl = 0; sl < 4; ++sl) {
                unsigned cp = CP[sl];
                unsigned ncp = (cp == ui) ? m : cp;
                ncp = (cp == m) ? ui : ncp;
                CP[sl] = ncp;
            }

            // intersection prefix + overlap ballot
            float intr[4]; bool anyp = false;
            #pragma unroll
            for (int sl = 0; sl < 4; ++sl) {
                int p = sl * 64 + t;
                bool act = (p < NBOX) && (CP[sl] > ui);
                float xx1 = fmaxf(pvx1, X1[sl]);
                float yy1 = fmaxf(pvy1, Y1[sl]);
                float xx2 = fminf(pvx2, X2[sl]);
                float yy2 = fminf(pvy2, Y2[sl]);
                float inter = fmaxf(0.0f, xx2 - xx1 + 1.0f) *
                              fmaxf(0.0f, yy2 - yy1 + 1.0f);
                intr[sl] = inter;
                anyp |= (act && inter != 0.0f);
            }
            // skip is bit-exact: inter==0 -> iou=0 -> w=expf(-0.0f)=1.0f
            if (__ballot(anyp) != 0ull) {
                #pragma unroll
                for (int sl = 0; sl < 4; ++sl) {
                    int p = sl * 64 + t;
                    if ((p < NBOX) && (CP[sl] > ui)) {
                        float iou = intr[sl] / (area_i + AR[sl] - intr[sl]);
                        float w = expf(-(iou * iou) / 0.5f);
                        SC[sl] = w * SC[sl];
                    }
                }
            }
        }

        // ---- write outputs: box with final cpos q lands at position q ----
        float* ob  = out + (size_t)b * NBOX * 4;
        float* oc  = out + (size_t)NBATCH * NBOX * 4 + b * NBOX;
        float* os  = out + (size_t)NBATCH * NBOX * 5 + b * NBOX;
        float* okp = out + (size_t)NBATCH * NBOX * 6 + b * NBOX;
        #pragma unroll
        for (int sl = 0; sl < 4; ++sl) {
            int p = sl * 64 + t;
            if (p < NBOX) {
                unsigned q = CP[sl];
                ob[q * 4 + 0] = X1[sl];
                ob[q * 4 + 1] = Y1[sl];
                ob[q * 4 + 2] = X2[sl];
                ob[q * 4 + 3] = Y2[sl];
                oc[q]  = CL4[sl];
                os[q]  = SC[sl];
                okp[q] = (SC[sl] > 0.1f) ? 1.0f : 0.0f;
            }
        }
    }
}

// ===========================================================================
// FALLBACK PATH (round-2 verified kernels, verbatim) — used if ws too small
// ===========================================================================
__global__ __launch_bounds__(1024) void ktopk(const float* __restrict__ x,
                                              float* __restrict__ out) {
    __shared__ unsigned hist[4096];
    __shared__ unsigned long long cand[CAP];
    __shared__ int shB, shB2;
    __shared__ unsigned shAbove, shNcand, shNc;

    const int slice = blockIdx.x;
    const int b = slice >> 1, s = slice & 1;
    const int t = threadIdx.x;
    const float* xb = x + (size_t)slice * SLICE_STRIDE;
    const float4* xb4 = (const float4*)xb;
    const int N4 = HM / 4;

    if (t == 0) { shB = 0; shB2 = 0; shAbove = 0u; shNcand = 0u; shNc = 0u; }
    for (int i = t; i < 4096; i += 1024) hist[i] = 0u;
    __syncthreads();

    for (int i = t; i < N4; i += 1024) {
        float4 v = xb4[i];
        float a[4] = {v.x, v.y, v.z, v.w};
        #pragma unroll
        for (int c_ = 0; c_ < 4; ++c_) {
            unsigned vk = fkey(a[c_]);
            atomicAdd(&hist[vk >> 20], 1u);
        }
    }
    __syncthreads();

    {
        unsigned* tmp = (unsigned*)cand;
        unsigned* src = hist;
        unsigned* dst = tmp;
        for (int d = 1; d < 4096; d <<= 1) {
            for (int i = t; i < 4096; i += 1024) {
                unsigned v = src[i];
                if (i + d < 4096) v += src[i + d];
                dst[i] = v;
            }
            __syncthreads();
            unsigned* sw = src; src = dst; dst = sw;
        }
        for (int i = t; i < 4096; i += 1024) {
            unsigned sb = src[i];
            unsigned sn = (i < 4095) ? src[i + 1] : 0u;
            if (sb >= TOPK && sn < TOPK) { shB = i; shAbove = sn; shNcand = sb; }
        }
        __syncthreads();
    }

    const bool refine = (shNcand > CAP);
    if (refine) {
        for (int i = t; i < 4096; i += 1024) hist[i] = 0u;
        __syncthreads();
        const unsigned Bv = (unsigned)shB;
        for (int i = t; i < N4; i += 1024) {
            float4 v = xb4[i];
            float a[4] = {v.x, v.y, v.z, v.w};
            #pragma unroll
            for (int c_ = 0; c_ < 4; ++c_) {
                unsigned vk = fkey(a[c_]);
                if ((vk >> 20) == Bv) atomicAdd(&hist[(vk >> 8) & 0xFFFu], 1u);
            }
        }
        __syncthreads();
        if (t == 0) {
            unsigned need = TOPK - shAbove, cum = 0u;
            int b2 = 4095;
            for (; b2 >= 0; --b2) { cum += hist[b2]; if (cum >= need) break; }
            shB2 = (b2 < 0) ? 0 : b2;
            shNcand = shAbove + cum;
        }
        __syncthreads();
    }

    {
        const unsigned Bv = (unsigned)shB;
        const unsigned B2v = refine ? (unsigned)shB2 : 0u;
        for (int i = t; i < N4; i += 1024) {
            float4 v = xb4[i];
            float a[4] = {v.x, v.y, v.z, v.w};
            #pragma unroll
            for (int c_ = 0; c_ < 4; ++c_) {
                unsigned vk = fkey(a[c_]);
                unsigned bin = vk >> 20;
                bool q = refine ? (bin > Bv || (bin == Bv && ((vk >> 8) & 0xFFFu) >= B2v))
                                : (bin >= Bv);
                if (q) {
                    unsigned pos = atomicAdd(&shNc, 1u);
                    if (pos < CAP)
                        cand[pos] = ((unsigned long long)vk << 32) |
                                    (unsigned)~(unsigned)(i * 4 + c_);
                }
            }
        }
        __syncthreads();
    }

    unsigned nc = shNc; if (nc > CAP) nc = CAP;
    int P = 128; while (P < (int)nc) P <<= 1;
    for (int i = (int)nc + t; i < P; i += 1024) cand[i] = 0ull;
    __syncthreads();
    for (int k = 2; k <= P; k <<= 1) {
        for (int j = k >> 1; j > 0; j >>= 1) {
            for (int i = t; i < P; i += 1024) {
                int ixj = i ^ j;
                if (ixj > i) {
                    unsigned long long a = cand[i], c2 = cand[ixj];
                    bool sw = ((i & k) == 0) ? (a < c2) : (a > c2);
                    if (sw) { cand[i] = c2; cand[ixj] = a; }
                }
            }
            __syncthreads();
        }
    }

    if (t < TOPK) {
        unsigned long long K = cand[t];
        unsigned vk = (unsigned)(K >> 32);
        unsigned idx = ~((unsigned)K);
        unsigned u = (vk & 0x80000000u) ? (vk & 0x7FFFFFFFu) : ~vk;
        float z = __uint_as_float(u);
        int c = (int)(idx >> 16);
        int rem = (int)(idx & 0xFFFFu);
        float ysf = (float)(rem >> 8);
        float xsf = (float)(rem & 255);
        float offx = xb[3 * HW + rem];
        float offy = xb[4 * HW + rem];
        float bw = xb[5 * HW + rem] * 4.0f;
        float bh = xb[6 * HW + rem] * 4.0f;
        float cx = (xsf + offx) * 4.0f;
        float cy = (ysf + offy) * 4.0f;
        int slot = s * TOPK + t;
        float* ob = out + (size_t)b * NBOX * 4;
        float* oc = out + (size_t)NBATCH * NBOX * 4 + b * NBOX;
        float* os = out + (size_t)NBATCH * NBOX * 5 + b * NBOX;
        ob[slot * 4 + 0] = cx - bw * 0.5f;
        ob[slot * 4 + 1] = cy - bh * 0.5f;
        ob[slot * 4 + 2] = cx + bw * 0.5f;
        ob[slot * 4 + 3] = cy + bh * 0.5f;
        float sg = 1.0f / (1.0f + expf(-z));
        os[slot] = (sg > 0.1f) ? sg : 0.0f;
        oc[slot] = (float)c;
    }
}

__global__ __launch_bounds__(64) void knms(float* __restrict__ out) {
    __shared__ float bxs[NBOX][4];
    __shared__ float scs[NBOX];
    __shared__ float cl[NBOX];

    const int b = blockIdx.x, t = threadIdx.x;
    float* ob  = out + (size_t)b * NBOX * 4;
    float* oc  = out + (size_t)NBATCH * NBOX * 4 + b * NBOX;
    float* os  = out + (size_t)NBATCH * NBOX * 5 + b * NBOX;
    float* okp = out + (size_t)NBATCH * NBOX * 6 + b * NBOX;

    for (int p = t; p < NBOX; p += 64) {
        bxs[p][0] = ob[p * 4 + 0];
        bxs[p][1] = ob[p * 4 + 1];
        bxs[p][2] = ob[p * 4 + 2];
        bxs[p][3] = ob[p * 4 + 3];
        scs[p] = os[p];
        cl[p]  = oc[p];
    }
    __syncthreads();

    unsigned long long local = 0ull;
    for (int p = t; p < NBOX; p += 64) {
        unsigned long long k =
            ((unsigned long long)__float_as_uint(scs[p]) << 32) | (unsigned)~(unsigned)p;
        if (k > local) local = k;
    }
    #pragma unroll
    for (int off = 32; off > 0; off >>= 1) {
        unsigned long long o = __shfl_xor(local, off);
        if (o > local) local = o;
    }
    unsigned long long kmax = local;

    for (int i = 0; i < NBOX; ++i) {
        int m = (int)(~((unsigned)kmax));
        if (t == 0 && m != i) {
            #pragma unroll
            for (int k = 0; k < 4; ++k) {
                float tmp = bxs[i][k]; bxs[i][k] = bxs[m][k]; bxs[m][k] = tmp;
            }
            float ts = scs[i]; scs[i] = scs[m]; scs[m] = ts;
            float tc = cl[i];  cl[i]  = cl[m];  cl[m]  = tc;
        }
        __syncthreads();

        float b0 = bxs[i][0], b1 = bxs[i][1], b2 = bxs[i][2], b3 = bxs[i][3];
        float area_i = (b2 - b0 + 1.0f) * (b3 - b1 + 1.0f);

        local = 0ull;
        for (int p = i + 1 + t; p < NBOX; p += 64) {
            float x1 = bxs[p][0], y1 = bxs[p][1], x2 = bxs[p][2], y2 = bxs[p][3];
            float areas = (x2 - x1 + 1.0f) * (y2 - y1 + 1.0f);
            float xx1 = fmaxf(b0, x1);
            float yy1 = fmaxf(b1, y1);
            float xx2 = fminf(b2, x2);
            float yy2 = fminf(b3, y2);
            float inter = fmaxf(0.0f, xx2 - xx1 + 1.0f) * fmaxf(0.0f, yy2 - yy1 + 1.0f);
            float iou = inter / (area_i + areas - inter);
            float w = expf(-(iou * iou) / 0.5f);
            float ns = w * scs[p];
            scs[p] = ns;
            unsigned long long k =
                ((unsigned long long)__float_as_uint(ns) << 32) | (unsigned)~(unsigned)p;
            if (k > local) local = k;
        }
        __syncthreads();
        #pragma unroll
        for (int off = 32; off > 0; off >>= 1) {
            unsigned long long o = __shfl_xor(local, off);
            if (o > local) local = o;
        }
        kmax = local;
    }
    __syncthreads();

    for (int p = t; p < NBOX; p += 64) {
        ob[p * 4 + 0] = bxs[p][0];
        ob[p * 4 + 1] = bxs[p][1];
        ob[p * 4 + 2] = bxs[p][2];
        ob[p * 4 + 3] = bxs[p][3];
        oc[p]  = cl[p];
        os[p]  = scs[p];
        okp[p] = (scs[p] > 0.1f) ? 1.0f : 0.0f;
    }
}

extern "C" void kernel_launch(void* const* d_in, const int* in_sizes, int n_in,
                              void* d_out, int out_size, void* d_ws, size_t ws_size,
                              hipStream_t stream) {
    const float* x = (const float*)d_in[0];
    float* out = (float*)d_out;
    if (d_ws != nullptr && ws_size >= WS_NEED) {
        kcollect<<<64 * NPART, 1024, 0, stream>>>(x, (unsigned long long*)d_ws);
        knms6<<<NBATCH, 1024, 0, stream>>>(x, (const unsigned long long*)d_ws, out);
    } else {
        ktopk<<<2 * NBATCH, 1024, 0, stream>>>(x, out);
        knms<<<NBATCH, 64, 0, stream>>>(out);
    }
}